// Round 4
// baseline (204.782 us; speedup 1.0000x reference)
//
#include <hip/hip_runtime.h>
#include <math.h>

// Problem constants (from reference setup_inputs)
constexpr int B = 2, S = 5, C = 256, H = 200, W = 200;
constexpr int KW = 7;              // window
constexpr int HB = 29, WB = 29;    // ceil(203/7)
constexpr int HID = 16;
constexpr int NW = HB * WB;        // 841

// ---------------------------------------------------------------------------
// Kernel 1: per-window channel sums, one 256-thread block per (s,c) plane of
// batch `b`. Phase A: thread owns (hb, x4): 7 vertically-adjacent float4
// loads summed into LDS colgroup[29][200]. ONE barrier. Phase B: horizontal
// 7-window sums -> gsum (contiguous).
// gsum layout: [B*S*C][841]
// ---------------------------------------------------------------------------
__global__ __launch_bounds__(256) void k_winsum(const float* __restrict__ feats,
                                                float* __restrict__ gsum,
                                                int b) {
    const int blk = b * S * C + (int)blockIdx.x;   // (b*S+s)*C + c
    const float* src = feats + (size_t)blk * (H * W);

    __shared__ float colg[HB * W];              // 29*200 floats = 23.2 KB

    const int tid = (int)threadIdx.x;

    // Phase A: 29*50 = 1450 items
    for (int q = tid; q < HB * (W / 4); q += 256) {
        int hb = q / (W / 4);
        int x4 = q - hb * (W / 4);
        int y0 = hb * KW;
        float4 a = make_float4(0.f, 0.f, 0.f, 0.f);
#pragma unroll
        for (int i = 0; i < KW; ++i) {
            int y = y0 + i;
            if (y < H) {
                float4 v = ((const float4*)(src + (size_t)y * W))[x4];
                a.x += v.x; a.y += v.y; a.z += v.z; a.w += v.w;
            }
        }
        ((float4*)(colg + hb * W))[x4] = a;
    }
    __syncthreads();

    // Phase B: 841 horizontal window sums, contiguous store
    float* dst = gsum + (size_t)blk * NW;
    for (int p = tid; p < NW; p += 256) {
        int hb = p / WB;
        int wb = p - hb * WB;
        int x0 = wb * KW;
        float s = 0.f;
#pragma unroll
        for (int j = 0; j < KW; ++j) {
            int x = x0 + j;
            if (x < W) s += colg[hb * W + x];
        }
        dst[p] = s;
    }
}

// ---------------------------------------------------------------------------
// Kernel 2: MLP + softmax over wb. One 256-thread block per (s,hb) of batch
// b. Thread (cg, wb), cg=0..7: partial acc[16] over 32 channels; LDS reduce
// over cg; lanes 0..28 compute logits + softmax over wb.
// ---------------------------------------------------------------------------
__global__ __launch_bounds__(256) void k_weights(const float* __restrict__ gsum,
                                                 const float* __restrict__ w1,
                                                 const float* __restrict__ b1,
                                                 const float* __restrict__ w2,
                                                 const float* __restrict__ b2,
                                                 float* __restrict__ weights,
                                                 int b) {
    int blk = blockIdx.x;
    int hb = blk % HB;
    int s  = blk / HB;
    const int bs = b * S + s;

    __shared__ float w1s[HID * C];        // 16 KB
    __shared__ float part[8 * HID * WB];  // 14.5 KB
    __shared__ float lg[WB];

    const int tid = (int)threadIdx.x;
    for (int i = tid; i < HID * C; i += 256) w1s[i] = w1[i];
    __syncthreads();

    if (tid < 8 * WB) {                   // 232 active
        const int cg = tid / WB;          // 0..7
        const int wb = tid - cg * WB;     // 0..28
        float acc[HID];
#pragma unroll
        for (int d = 0; d < HID; ++d) acc[d] = 0.f;
        const float* g = gsum + (size_t)bs * C * NW + hb * WB + wb;
        const int c0 = cg * (C / 8);
        for (int c = c0; c < c0 + C / 8; ++c) {
            float gc = g[(size_t)c * NW];
#pragma unroll
            for (int d = 0; d < HID; ++d) acc[d] += gc * w1s[d * C + c];
        }
#pragma unroll
        for (int d = 0; d < HID; ++d) part[(cg * HID + d) * WB + wb] = acc[d];
    }
    __syncthreads();

    if (tid < WB) {
        float logit = b2[0];
#pragma unroll
        for (int d = 0; d < HID; ++d) {
            float a = 0.f;
#pragma unroll
            for (int cg = 0; cg < 8; ++cg) a += part[(cg * HID + d) * WB + tid];
            float h = a * (1.0f / 49.0f) + b1[d];
            logit += fmaxf(h, 0.0f) * w2[d];
        }
        lg[tid] = logit;
    }
    __syncthreads();
    if (tid < WB) {
        float m = -INFINITY;
        for (int t = 0; t < WB; ++t) m = fmaxf(m, lg[t]);
        float sum = 0.f;
        for (int t = 0; t < WB; ++t) sum += expf(lg[t] - m);
        weights[(size_t)bs * NW + hb * WB + tid] = expf(lg[tid] - m) / sum;
    }
}

// ---------------------------------------------------------------------------
// Kernel 3: weighted fusion for batch b. Output row y = i*29+hb needs exactly
// one input row y_in = hb*7+i per slice. Block = (c, group of 4 output rows).
// Stage 5 slices x 4 input rows into LDS (coalesced float4, L3-resident from
// k_winsum), permute columns via LDS gather, write output rows as float4.
// ---------------------------------------------------------------------------
constexpr int RPB = 4;  // output rows per block
__global__ __launch_bounds__(256) void k_fuse(const float* __restrict__ feats,
                                              const float* __restrict__ weights,
                                              float* __restrict__ out,
                                              int b) {
    int blk = blockIdx.x;
    const int g = blk % (H / RPB);
    const int c = blk / (H / RPB);
    const int y0 = g * RPB;

    __shared__ float buf[S][RPB][W];     // 16 KB
    __shared__ float wsl[S][RPB][WB];    // 2.3 KB

    const int tid = (int)threadIdx.x;
    const size_t plane = (size_t)H * W;
    const size_t sstride = (size_t)C * plane;
    const float* f0 = feats + ((size_t)b * S * C + c) * plane;

    // stage input rows (float4, coalesced); zero the padded rows
    for (int q = tid; q < S * RPB * (W / 4); q += 256) {  // 1000 float4
        int s  = q / (RPB * (W / 4));
        int r  = q - s * (RPB * (W / 4));
        int yy = r / (W / 4);
        int xq = r - yy * (W / 4);
        int y  = y0 + yy;
        int i  = y / HB;
        int hb = y - i * HB;
        int y_in = hb * KW + i;
        float4 v = make_float4(0.f, 0.f, 0.f, 0.f);
        if (y_in < H)
            v = ((const float4*)(f0 + (size_t)s * sstride + (size_t)y_in * W))[xq];
        ((float4*)&buf[s][yy][0])[xq] = v;
    }
    // stage the needed weight rows
    for (int q = tid; q < S * RPB * WB; q += 256) {       // 580 floats
        int s  = q / (RPB * WB);
        int r  = q - s * (RPB * WB);
        int yy = r / WB;
        int wb = r - yy * WB;
        int hb = (y0 + yy) % HB;
        wsl[s][yy][wb] = weights[((size_t)(b * S + s) * HB + hb) * WB + wb];
    }
    __syncthreads();

    float* o = out + ((size_t)b * C + c) * plane + (size_t)y0 * W;
    for (int p = tid; p < RPB * (W / 4); p += 256) {      // 200 float4 outputs
        int yy = p / (W / 4);
        int x0 = (p - yy * (W / 4)) * 4;
        float4 r;
        float* rp = (float*)&r;
#pragma unroll
        for (int u = 0; u < 4; ++u) {
            int x  = x0 + u;
            int j  = x / WB;
            int wb = x - j * WB;
            int x_in = wb * KW + j;
            float acc = 0.f;
            if (x_in < W) {
#pragma unroll
                for (int s = 0; s < S; ++s)
                    acc += buf[s][yy][x_in] * wsl[s][yy][wb];
            }
            rp[u] = acc;
        }
        ((float4*)(o + (size_t)yy * W))[x0 / 4] = r;
    }
}

// ---------------------------------------------------------------------------
extern "C" void kernel_launch(void* const* d_in, const int* in_sizes, int n_in,
                              void* d_out, int out_size, void* d_ws, size_t ws_size,
                              hipStream_t stream) {
    const float* feats = (const float*)d_in[0];
    const float* w1    = (const float*)d_in[1];
    const float* b1    = (const float*)d_in[2];
    const float* w2    = (const float*)d_in[3];
    const float* b2    = (const float*)d_in[4];
    float* out = (float*)d_out;

    // Workspace layout
    float* gsum    = (float*)d_ws;                      // B*S*C*841 floats
    float* weights = gsum + (size_t)B * S * C * NW;     // B*S*841 floats

    // Per-batch chain: batch b's 204.8 MB of feats stays L3-resident between
    // k_winsum's read and k_fuse's re-read (256 MB Infinity Cache).
    for (int b = 0; b < B; ++b) {
        hipLaunchKernelGGL(k_winsum, dim3(S * C), dim3(256), 0, stream,
                           feats, gsum, b);
        hipLaunchKernelGGL(k_weights, dim3(S * HB), dim3(256), 0, stream,
                           gsum, w1, b1, w2, b2, weights, b);
        hipLaunchKernelGGL(k_fuse, dim3(C * (H / RPB)), dim3(256), 0, stream,
                           feats, weights, out, b);
    }
}

// Round 5
// 176.772 us; speedup vs baseline: 1.1585x; 1.1585x over previous
//
#include <hip/hip_runtime.h>
#include <math.h>

// Problem constants (from reference setup_inputs)
constexpr int B = 2, S = 5, C = 256, H = 200, W = 200;
constexpr int KW = 7;              // window
constexpr int HB = 29, WB = 29;    // ceil(203/7)
constexpr int HID = 16;
constexpr int NW = HB * WB;        // 841

// ---------------------------------------------------------------------------
// Kernel 1: per-window channel sums, one 256-thread block per (b,s,c) plane.
// Phase A: thread owns (hb, x4): 7 vertically-adjacent float4 loads summed
// into LDS colg[29][200]. ONE barrier. Phase B: horizontal 7-window sums ->
// gsum (contiguous). gsum layout: [B*S*C][841]
// ---------------------------------------------------------------------------
__global__ __launch_bounds__(256) void k_winsum(const float* __restrict__ feats,
                                                float* __restrict__ gsum) {
    const int blk = (int)blockIdx.x;            // (b*S+s)*C + c
    const float* src = feats + (size_t)blk * (H * W);

    __shared__ float colg[HB * W];              // 23.2 KB

    const int tid = (int)threadIdx.x;

    // Phase A: 29*50 = 1450 items
    for (int q = tid; q < HB * (W / 4); q += 256) {
        int hb = q / (W / 4);
        int x4 = q - hb * (W / 4);
        int y0 = hb * KW;
        float4 a = make_float4(0.f, 0.f, 0.f, 0.f);
#pragma unroll
        for (int i = 0; i < KW; ++i) {
            int y = y0 + i;
            if (y < H) {
                float4 v = ((const float4*)(src + (size_t)y * W))[x4];
                a.x += v.x; a.y += v.y; a.z += v.z; a.w += v.w;
            }
        }
        ((float4*)(colg + hb * W))[x4] = a;
    }
    __syncthreads();

    // Phase B: 841 horizontal window sums, contiguous store
    float* dst = gsum + (size_t)blk * NW;
    for (int p = tid; p < NW; p += 256) {
        int hb = p / WB;
        int wb = p - hb * WB;
        int x0 = wb * KW;
        float s = 0.f;
#pragma unroll
        for (int j = 0; j < KW; ++j) {
            int x = x0 + j;
            if (x < W) s += colg[hb * W + x];
        }
        dst[p] = s;
    }
}

// ---------------------------------------------------------------------------
// Kernel 2: MLP + softmax over wb. One 256-thread block per (b,s,hb).
// Thread (cg, wb), cg=0..7: partial acc[16] over 32 channels; LDS reduce
// over cg; lanes 0..28 compute logits + softmax over wb.
// ---------------------------------------------------------------------------
__global__ __launch_bounds__(256) void k_weights(const float* __restrict__ gsum,
                                                 const float* __restrict__ w1,
                                                 const float* __restrict__ b1,
                                                 const float* __restrict__ w2,
                                                 const float* __restrict__ b2,
                                                 float* __restrict__ weights) {
    int blk = blockIdx.x;
    int hb = blk % HB; blk /= HB;
    int s  = blk % S;
    int b  = blk / S;
    const int bs = b * S + s;

    __shared__ float w1s[HID * C];        // 16 KB
    __shared__ float part[8 * HID * WB];  // 14.5 KB
    __shared__ float lg[WB];

    const int tid = (int)threadIdx.x;
    for (int i = tid; i < HID * C; i += 256) w1s[i] = w1[i];
    __syncthreads();

    if (tid < 8 * WB) {                   // 232 active
        const int cg = tid / WB;          // 0..7
        const int wb = tid - cg * WB;     // 0..28
        float acc[HID];
#pragma unroll
        for (int d = 0; d < HID; ++d) acc[d] = 0.f;
        const float* g = gsum + (size_t)bs * C * NW + hb * WB + wb;
        const int c0 = cg * (C / 8);
#pragma unroll 4
        for (int c = c0; c < c0 + C / 8; ++c) {
            float gc = g[(size_t)c * NW];
#pragma unroll
            for (int d = 0; d < HID; ++d) acc[d] += gc * w1s[d * C + c];
        }
#pragma unroll
        for (int d = 0; d < HID; ++d) part[(cg * HID + d) * WB + wb] = acc[d];
    }
    __syncthreads();

    if (tid < WB) {
        float logit = b2[0];
#pragma unroll
        for (int d = 0; d < HID; ++d) {
            float a = 0.f;
#pragma unroll
            for (int cg = 0; cg < 8; ++cg) a += part[(cg * HID + d) * WB + tid];
            float h = a * (1.0f / 49.0f) + b1[d];
            logit += fmaxf(h, 0.0f) * w2[d];
        }
        lg[tid] = logit;
    }
    __syncthreads();
    if (tid < WB) {
        float m = -INFINITY;
        for (int t = 0; t < WB; ++t) m = fmaxf(m, lg[t]);
        float sum = 0.f;
        for (int t = 0; t < WB; ++t) sum += expf(lg[t] - m);
        weights[(size_t)bs * NW + hb * WB + tid] = expf(lg[tid] - m) / sum;
    }
}

// ---------------------------------------------------------------------------
// Kernel 3: weighted fusion. Output row y = i*29+hb needs exactly one input
// row y_in = hb*7+i per slice. Block = (b, c, group of 4 output rows), with
// the mapping REVERSED (b=1, high c first) so the earliest fuse blocks read
// the planes winsum touched most recently (L3-retention probe).
// Stage 5 slices x 4 input rows into LDS (coalesced float4), permute columns
// via LDS gather, write output rows as float4.
// ---------------------------------------------------------------------------
constexpr int RPB = 4;  // output rows per block
__global__ __launch_bounds__(256) void k_fuse(const float* __restrict__ feats,
                                              const float* __restrict__ weights,
                                              float* __restrict__ out) {
    int blk = blockIdx.x;
    const int g = blk % (H / RPB); blk /= (H / RPB);
    const int c = (C - 1) - (blk % C);
    const int b = (B - 1) - (blk / C);
    const int y0 = g * RPB;

    __shared__ float buf[S][RPB][W];     // 16 KB
    __shared__ float wsl[S][RPB][WB];    // 2.3 KB

    const int tid = (int)threadIdx.x;
    const size_t plane = (size_t)H * W;
    const size_t sstride = (size_t)C * plane;
    const float* f0 = feats + ((size_t)b * S * C + c) * plane;

    // stage input rows (float4, coalesced); zero the padded rows
    for (int q = tid; q < S * RPB * (W / 4); q += 256) {  // 1000 float4
        int s  = q / (RPB * (W / 4));
        int r  = q - s * (RPB * (W / 4));
        int yy = r / (W / 4);
        int xq = r - yy * (W / 4);
        int y  = y0 + yy;
        int i  = y / HB;
        int hb = y - i * HB;
        int y_in = hb * KW + i;
        float4 v = make_float4(0.f, 0.f, 0.f, 0.f);
        if (y_in < H)
            v = ((const float4*)(f0 + (size_t)s * sstride + (size_t)y_in * W))[xq];
        ((float4*)&buf[s][yy][0])[xq] = v;
    }
    // stage the needed weight rows
    for (int q = tid; q < S * RPB * WB; q += 256) {       // 580 floats
        int s  = q / (RPB * WB);
        int r  = q - s * (RPB * WB);
        int yy = r / WB;
        int wb = r - yy * WB;
        int hb = (y0 + yy) % HB;
        wsl[s][yy][wb] = weights[((size_t)(b * S + s) * HB + hb) * WB + wb];
    }
    __syncthreads();

    float* o = out + ((size_t)b * C + c) * plane + (size_t)y0 * W;
    for (int p = tid; p < RPB * (W / 4); p += 256) {      // 200 float4 outputs
        int yy = p / (W / 4);
        int x0 = (p - yy * (W / 4)) * 4;
        float4 r;
        float* rp = (float*)&r;
#pragma unroll
        for (int u = 0; u < 4; ++u) {
            int x  = x0 + u;
            int j  = x / WB;
            int wb = x - j * WB;
            int x_in = wb * KW + j;
            float acc = 0.f;
            if (x_in < W) {
#pragma unroll
                for (int s = 0; s < S; ++s)
                    acc += buf[s][yy][x_in] * wsl[s][yy][wb];
            }
            rp[u] = acc;
        }
        ((float4*)(o + (size_t)yy * W))[x0 / 4] = r;
    }
}

// ---------------------------------------------------------------------------
extern "C" void kernel_launch(void* const* d_in, const int* in_sizes, int n_in,
                              void* d_out, int out_size, void* d_ws, size_t ws_size,
                              hipStream_t stream) {
    const float* feats = (const float*)d_in[0];
    const float* w1    = (const float*)d_in[1];
    const float* b1    = (const float*)d_in[2];
    const float* w2    = (const float*)d_in[3];
    const float* b2    = (const float*)d_in[4];
    float* out = (float*)d_out;

    // Workspace layout
    float* gsum    = (float*)d_ws;                      // B*S*C*841 floats
    float* weights = gsum + (size_t)B * S * C * NW;     // B*S*841 floats

    // Kernel 1: window sums (one block per plane, single barrier)
    hipLaunchKernelGGL(k_winsum, dim3(B * S * C), dim3(256), 0, stream, feats, gsum);
    // Kernel 2: MLP + softmax -> weights
    hipLaunchKernelGGL(k_weights, dim3(B * S * HB), dim3(256), 0, stream,
                       gsum, w1, b1, w2, b2, weights);
    // Kernel 3: weighted fusion (reversed order for L3-retention probe)
    hipLaunchKernelGGL(k_fuse, dim3(B * C * (H / RPB)), dim3(256), 0, stream,
                       feats, weights, out);
}

// Round 6
// 176.277 us; speedup vs baseline: 1.1617x; 1.0028x over previous
//
#include <hip/hip_runtime.h>
#include <math.h>

// Problem constants (from reference setup_inputs)
constexpr int B = 2, S = 5, C = 256, H = 200, W = 200;
constexpr int KW = 7;              // window
constexpr int HB = 29, WB = 29;    // ceil(203/7)
constexpr int HID = 16;
constexpr int NW = HB * WB;        // 841

// ---------------------------------------------------------------------------
// Kernel 1: per-window channel sums, one 512-thread block per (b,s,c) plane.
// 512 threads -> 8 waves/block, 4 blocks/CU (LDS 4x23.2=93KB) = 32 waves/CU
// = 100% occupancy (was 75% at 256 threads).
// Phase A: thread owns (hb, x4): 7 vertically-adjacent float4 loads summed
// into LDS colg[29][200]. ONE barrier. Phase B: horizontal 7-window sums ->
// gsum (contiguous). gsum layout: [B*S*C][841]
// ---------------------------------------------------------------------------
__global__ __launch_bounds__(512) void k_winsum(const float* __restrict__ feats,
                                                float* __restrict__ gsum) {
    const int blk = (int)blockIdx.x;            // (b*S+s)*C + c
    const float* src = feats + (size_t)blk * (H * W);

    __shared__ float colg[HB * W];              // 23.2 KB

    const int tid = (int)threadIdx.x;

    // Phase A: 29*50 = 1450 items
    for (int q = tid; q < HB * (W / 4); q += 512) {
        int hb = q / (W / 4);
        int x4 = q - hb * (W / 4);
        int y0 = hb * KW;
        float4 a = make_float4(0.f, 0.f, 0.f, 0.f);
#pragma unroll
        for (int i = 0; i < KW; ++i) {
            int y = y0 + i;
            if (y < H) {
                float4 v = ((const float4*)(src + (size_t)y * W))[x4];
                a.x += v.x; a.y += v.y; a.z += v.z; a.w += v.w;
            }
        }
        ((float4*)(colg + hb * W))[x4] = a;
    }
    __syncthreads();

    // Phase B: 841 horizontal window sums, contiguous store
    float* dst = gsum + (size_t)blk * NW;
    for (int p = tid; p < NW; p += 512) {
        int hb = p / WB;
        int wb = p - hb * WB;
        int x0 = wb * KW;
        float s = 0.f;
#pragma unroll
        for (int j = 0; j < KW; ++j) {
            int x = x0 + j;
            if (x < W) s += colg[hb * W + x];
        }
        dst[p] = s;
    }
}

// ---------------------------------------------------------------------------
// Kernel 2: MLP + softmax over wb. One 256-thread block per (b,s,hb).
// Thread (cg, wb), cg=0..7: partial acc[16] over 32 channels; LDS reduce
// over cg; lanes 0..28 compute logits + softmax over wb.
// ---------------------------------------------------------------------------
__global__ __launch_bounds__(256) void k_weights(const float* __restrict__ gsum,
                                                 const float* __restrict__ w1,
                                                 const float* __restrict__ b1,
                                                 const float* __restrict__ w2,
                                                 const float* __restrict__ b2,
                                                 float* __restrict__ weights) {
    int blk = blockIdx.x;
    int hb = blk % HB; blk /= HB;
    int s  = blk % S;
    int b  = blk / S;
    const int bs = b * S + s;

    __shared__ float w1s[HID * C];        // 16 KB
    __shared__ float part[8 * HID * WB];  // 14.5 KB
    __shared__ float lg[WB];

    const int tid = (int)threadIdx.x;
    for (int i = tid; i < HID * C; i += 256) w1s[i] = w1[i];
    __syncthreads();

    if (tid < 8 * WB) {                   // 232 active
        const int cg = tid / WB;          // 0..7
        const int wb = tid - cg * WB;     // 0..28
        float acc[HID];
#pragma unroll
        for (int d = 0; d < HID; ++d) acc[d] = 0.f;
        const float* g = gsum + (size_t)bs * C * NW + hb * WB + wb;
        const int c0 = cg * (C / 8);
#pragma unroll 4
        for (int c = c0; c < c0 + C / 8; ++c) {
            float gc = g[(size_t)c * NW];
#pragma unroll
            for (int d = 0; d < HID; ++d) acc[d] += gc * w1s[d * C + c];
        }
#pragma unroll
        for (int d = 0; d < HID; ++d) part[(cg * HID + d) * WB + wb] = acc[d];
    }
    __syncthreads();

    if (tid < WB) {
        float logit = b2[0];
#pragma unroll
        for (int d = 0; d < HID; ++d) {
            float a = 0.f;
#pragma unroll
            for (int cg = 0; cg < 8; ++cg) a += part[(cg * HID + d) * WB + tid];
            float h = a * (1.0f / 49.0f) + b1[d];
            logit += fmaxf(h, 0.0f) * w2[d];
        }
        lg[tid] = logit;
    }
    __syncthreads();
    if (tid < WB) {
        float m = -INFINITY;
        for (int t = 0; t < WB; ++t) m = fmaxf(m, lg[t]);
        float sum = 0.f;
        for (int t = 0; t < WB; ++t) sum += expf(lg[t] - m);
        weights[(size_t)bs * NW + hb * WB + tid] = expf(lg[tid] - m) / sum;
    }
}

// ---------------------------------------------------------------------------
// Kernel 3: weighted fusion. Output row y = i*29+hb needs exactly one input
// row y_in = hb*7+i per slice. Block = (b, c, group of 4 output rows), with
// the mapping REVERSED (b=1, high c first) so the earliest fuse blocks read
// the planes winsum touched most recently (L3 retention, proven R5).
// Stage 5 slices x 4 input rows into LDS (coalesced float4), permute columns
// via LDS gather, write output rows as float4.
// 18.3 KB LDS -> 8 blocks/CU x 4 waves = 100% occupancy.
// ---------------------------------------------------------------------------
constexpr int RPB = 4;  // output rows per block
__global__ __launch_bounds__(256) void k_fuse(const float* __restrict__ feats,
                                              const float* __restrict__ weights,
                                              float* __restrict__ out) {
    int blk = blockIdx.x;
    const int g = blk % (H / RPB); blk /= (H / RPB);
    const int c = (C - 1) - (blk % C);
    const int b = (B - 1) - (blk / C);
    const int y0 = g * RPB;

    __shared__ float buf[S][RPB][W];     // 16 KB
    __shared__ float wsl[S][RPB][WB];    // 2.3 KB

    const int tid = (int)threadIdx.x;
    const size_t plane = (size_t)H * W;
    const size_t sstride = (size_t)C * plane;
    const float* f0 = feats + ((size_t)b * S * C + c) * plane;

    // stage input rows (float4, coalesced); zero the padded rows
    for (int q = tid; q < S * RPB * (W / 4); q += 256) {  // 1000 float4
        int s  = q / (RPB * (W / 4));
        int r  = q - s * (RPB * (W / 4));
        int yy = r / (W / 4);
        int xq = r - yy * (W / 4);
        int y  = y0 + yy;
        int i  = y / HB;
        int hb = y - i * HB;
        int y_in = hb * KW + i;
        float4 v = make_float4(0.f, 0.f, 0.f, 0.f);
        if (y_in < H)
            v = ((const float4*)(f0 + (size_t)s * sstride + (size_t)y_in * W))[xq];
        ((float4*)&buf[s][yy][0])[xq] = v;
    }
    // stage the needed weight rows (29 contiguous floats each): float4-chunked
    // 20 rows x 8 float4-slots (last slot is 1 scalar) = 160 items
    for (int q = tid; q < S * RPB * 8; q += 256) {
        int s  = q / (RPB * 8);
        int r  = q - s * (RPB * 8);
        int yy = r / 8;
        int f4 = r - yy * 8;               // 0..7
        int hb = (y0 + yy) % HB;
        const float* wrow = weights + ((size_t)((b * S + s) * HB + hb)) * WB;
        float* drow = &wsl[s][yy][0];
        if (f4 < 7) {
            float4 v = make_float4(wrow[f4 * 4], wrow[f4 * 4 + 1],
                                   wrow[f4 * 4 + 2], wrow[f4 * 4 + 3]);
            drow[f4 * 4 + 0] = v.x; drow[f4 * 4 + 1] = v.y;
            drow[f4 * 4 + 2] = v.z; drow[f4 * 4 + 3] = v.w;
        } else {
            drow[28] = wrow[28];
        }
    }
    __syncthreads();

    float* o = out + ((size_t)b * C + c) * plane + (size_t)y0 * W;
    for (int p = tid; p < RPB * (W / 4); p += 256) {      // 200 float4 outputs
        int yy = p / (W / 4);
        int x0 = (p - yy * (W / 4)) * 4;
        float4 r;
        float* rp = (float*)&r;
#pragma unroll
        for (int u = 0; u < 4; ++u) {
            int x  = x0 + u;
            int j  = x / WB;
            int wb = x - j * WB;
            int x_in = wb * KW + j;
            float acc = 0.f;
            if (x_in < W) {
#pragma unroll
                for (int s = 0; s < S; ++s)
                    acc += buf[s][yy][x_in] * wsl[s][yy][wb];
            }
            rp[u] = acc;
        }
        ((float4*)(o + (size_t)yy * W))[x0 / 4] = r;
    }
}

// ---------------------------------------------------------------------------
extern "C" void kernel_launch(void* const* d_in, const int* in_sizes, int n_in,
                              void* d_out, int out_size, void* d_ws, size_t ws_size,
                              hipStream_t stream) {
    const float* feats = (const float*)d_in[0];
    const float* w1    = (const float*)d_in[1];
    const float* b1    = (const float*)d_in[2];
    const float* w2    = (const float*)d_in[3];
    const float* b2    = (const float*)d_in[4];
    float* out = (float*)d_out;

    // Workspace layout
    float* gsum    = (float*)d_ws;                      // B*S*C*841 floats
    float* weights = gsum + (size_t)B * S * C * NW;     // B*S*841 floats

    // Kernel 1: window sums (one 512-thread block per plane, 100% occupancy)
    hipLaunchKernelGGL(k_winsum, dim3(B * S * C), dim3(512), 0, stream, feats, gsum);
    // Kernel 2: MLP + softmax -> weights
    hipLaunchKernelGGL(k_weights, dim3(B * S * HB), dim3(256), 0, stream,
                       gsum, w1, b1, w2, b2, weights);
    // Kernel 3: weighted fusion (reversed order for L3 retention)
    hipLaunchKernelGGL(k_fuse, dim3(B * C * (H / RPB)), dim3(256), 0, stream,
                       feats, weights, out);
}

// Round 7
// 172.464 us; speedup vs baseline: 1.1874x; 1.0221x over previous
//
#include <hip/hip_runtime.h>
#include <math.h>

// Problem constants (from reference setup_inputs)
constexpr int B = 2, S = 5, C = 256, H = 200, W = 200;
constexpr int KW = 7;              // window
constexpr int HB = 29, WB = 29;    // ceil(203/7)
constexpr int HID = 16;
constexpr int NW = HB * WB;        // 841

// ---------------------------------------------------------------------------
// Kernel 1: per-window channel sums, one 512-thread block per (b,s,c) plane.
// Phase A: thread owns (hb, x4): 7 vertically-adjacent float4 loads summed
// into LDS colg[29][200]. ONE barrier. Phase B: horizontal 7-window sums ->
// gsum (contiguous). gsum layout: [B*S*C][841]
// (R6 showed this is BW-plateaued; unchanged.)
// ---------------------------------------------------------------------------
__global__ __launch_bounds__(512) void k_winsum(const float* __restrict__ feats,
                                                float* __restrict__ gsum) {
    const int blk = (int)blockIdx.x;            // (b*S+s)*C + c
    const float* src = feats + (size_t)blk * (H * W);

    __shared__ float colg[HB * W];              // 23.2 KB

    const int tid = (int)threadIdx.x;

    // Phase A: 29*50 = 1450 items
    for (int q = tid; q < HB * (W / 4); q += 512) {
        int hb = q / (W / 4);
        int x4 = q - hb * (W / 4);
        int y0 = hb * KW;
        float4 a = make_float4(0.f, 0.f, 0.f, 0.f);
#pragma unroll
        for (int i = 0; i < KW; ++i) {
            int y = y0 + i;
            if (y < H) {
                float4 v = ((const float4*)(src + (size_t)y * W))[x4];
                a.x += v.x; a.y += v.y; a.z += v.z; a.w += v.w;
            }
        }
        ((float4*)(colg + hb * W))[x4] = a;
    }
    __syncthreads();

    // Phase B: 841 horizontal window sums, contiguous store
    float* dst = gsum + (size_t)blk * NW;
    for (int p = tid; p < NW; p += 512) {
        int hb = p / WB;
        int wb = p - hb * WB;
        int x0 = wb * KW;
        float s = 0.f;
#pragma unroll
        for (int j = 0; j < KW; ++j) {
            int x = x0 + j;
            if (x < W) s += colg[hb * W + x];
        }
        dst[p] = s;
    }
}

// ---------------------------------------------------------------------------
// Kernel 2: MLP + softmax over wb. One 256-thread block per (b,s,hb).
// Thread (cg, wb), cg=0..7: partial acc[16] over 32 channels; LDS reduce
// over cg; lanes 0..28 compute logits + softmax over wb.
// ---------------------------------------------------------------------------
__global__ __launch_bounds__(256) void k_weights(const float* __restrict__ gsum,
                                                 const float* __restrict__ w1,
                                                 const float* __restrict__ b1,
                                                 const float* __restrict__ w2,
                                                 const float* __restrict__ b2,
                                                 float* __restrict__ weights) {
    int blk = blockIdx.x;
    int hb = blk % HB; blk /= HB;
    int s  = blk % S;
    int b  = blk / S;
    const int bs = b * S + s;

    __shared__ float w1s[HID * C];        // 16 KB
    __shared__ float part[8 * HID * WB];  // 14.5 KB
    __shared__ float lg[WB];

    const int tid = (int)threadIdx.x;
    for (int i = tid; i < HID * C; i += 256) w1s[i] = w1[i];
    __syncthreads();

    if (tid < 8 * WB) {                   // 232 active
        const int cg = tid / WB;          // 0..7
        const int wb = tid - cg * WB;     // 0..28
        float acc[HID];
#pragma unroll
        for (int d = 0; d < HID; ++d) acc[d] = 0.f;
        const float* g = gsum + (size_t)bs * C * NW + hb * WB + wb;
        const int c0 = cg * (C / 8);
#pragma unroll 4
        for (int c = c0; c < c0 + C / 8; ++c) {
            float gc = g[(size_t)c * NW];
#pragma unroll
            for (int d = 0; d < HID; ++d) acc[d] += gc * w1s[d * C + c];
        }
#pragma unroll
        for (int d = 0; d < HID; ++d) part[(cg * HID + d) * WB + wb] = acc[d];
    }
    __syncthreads();

    if (tid < WB) {
        float logit = b2[0];
#pragma unroll
        for (int d = 0; d < HID; ++d) {
            float a = 0.f;
#pragma unroll
            for (int cg = 0; cg < 8; ++cg) a += part[(cg * HID + d) * WB + tid];
            float h = a * (1.0f / 49.0f) + b1[d];
            logit += fmaxf(h, 0.0f) * w2[d];
        }
        lg[tid] = logit;
    }
    __syncthreads();
    if (tid < WB) {
        float m = -INFINITY;
        for (int t = 0; t < WB; ++t) m = fmaxf(m, lg[t]);
        float sum = 0.f;
        for (int t = 0; t < WB; ++t) sum += expf(lg[t] - m);
        weights[(size_t)bs * NW + hb * WB + tid] = expf(lg[tid] - m) / sum;
    }
}

// ---------------------------------------------------------------------------
// Kernel 3 (band-structured): block = (b, c, hb). The 7 output rows
// {y = i*29+hb} consume exactly the 7 CONTIGUOUS input rows hb*7..hb*7+6
// (5.6 KB contiguous per slice) and share ONE weight row per slice.
// 512 threads, LDS 28.6 KB -> 4 blocks/CU x 8 waves = 100% occupancy.
// Mapping reversed (b=1, high c first) for L3 retention (R5).
// ---------------------------------------------------------------------------
__global__ __launch_bounds__(512) void k_fuse(const float* __restrict__ feats,
                                              const float* __restrict__ weights,
                                              float* __restrict__ out) {
    int blk = blockIdx.x;
    const int hb = blk % HB; blk /= HB;
    const int c  = (C - 1) - (blk % C);
    const int b  = (B - 1) - (blk / C);

    __shared__ float buf[S][KW * W];     // 5 x 1400 floats = 28 KB
    __shared__ float wsl[S][WB];         // 580 B

    const int tid = (int)threadIdx.x;
    const size_t plane = (size_t)H * W;
    const size_t sstride = (size_t)C * plane;
    const float* f0 = feats + ((size_t)b * S * C + c) * plane;
    const int y_in0 = hb * KW;

    // stage: 5 slices x 350 float4, each slice a single contiguous 5.6 KB
    // stretch (rows y_in0..y_in0+6); zero rows past H (hb==28 tail)
    for (int q = tid; q < S * 350; q += 512) {
        int s = q / 350;
        int r = q - s * 350;               // float4 index within band
        int i = r / 50;                    // row in band
        float4 v = make_float4(0.f, 0.f, 0.f, 0.f);
        if (y_in0 + i < H)
            v = ((const float4*)(f0 + (size_t)s * sstride + (size_t)y_in0 * W))[r];
        ((float4*)&buf[s][0])[r] = v;
    }
    // one weight row per slice (all 7 output rows share it)
    if (tid < S * WB) {
        int s  = tid / WB;
        int wb = tid - s * WB;
        wsl[s][wb] = weights[((size_t)((b * S + s) * HB + hb)) * WB + wb];
    }
    __syncthreads();

    float* o = out + ((size_t)b * C + c) * plane;
    // outputs: rows y = i*29+hb (skip y>=200), 50 float4 per row
    for (int p = tid; p < KW * 50; p += 512) {
        int i = p / 50;
        int y = i * HB + hb;
        if (y < H) {
            int x0 = (p - i * 50) * 4;
            float4 r4;
            float* rp = (float*)&r4;
#pragma unroll
            for (int u = 0; u < 4; ++u) {
                int x  = x0 + u;
                int j  = x / WB;
                int wb = x - j * WB;
                int x_in = wb * KW + j;
                float acc = 0.f;
                if (x_in < W) {
#pragma unroll
                    for (int s = 0; s < S; ++s)
                        acc += buf[s][i * W + x_in] * wsl[s][wb];
                }
                rp[u] = acc;
            }
            ((float4*)(o + (size_t)y * W))[x0 / 4] = r4;
        }
    }
}

// ---------------------------------------------------------------------------
extern "C" void kernel_launch(void* const* d_in, const int* in_sizes, int n_in,
                              void* d_out, int out_size, void* d_ws, size_t ws_size,
                              hipStream_t stream) {
    const float* feats = (const float*)d_in[0];
    const float* w1    = (const float*)d_in[1];
    const float* b1    = (const float*)d_in[2];
    const float* w2    = (const float*)d_in[3];
    const float* b2    = (const float*)d_in[4];
    float* out = (float*)d_out;

    // Workspace layout
    float* gsum    = (float*)d_ws;                      // B*S*C*841 floats
    float* weights = gsum + (size_t)B * S * C * NW;     // B*S*841 floats

    // Kernel 1: window sums (one 512-thread block per plane)
    hipLaunchKernelGGL(k_winsum, dim3(B * S * C), dim3(512), 0, stream, feats, gsum);
    // Kernel 2: MLP + softmax -> weights
    hipLaunchKernelGGL(k_weights, dim3(B * S * HB), dim3(256), 0, stream,
                       gsum, w1, b1, w2, b2, weights);
    // Kernel 3: band-structured weighted fusion (reversed order for L3)
    hipLaunchKernelGGL(k_fuse, dim3(B * C * HB), dim3(512), 0, stream,
                       feats, weights, out);
}